// Round 1
// baseline (103.459 us; speedup 1.0000x reference)
//
#include <hip/hip_runtime.h>

// Problem constants (from reference): B=4, LQ=256, LK=512, DQ=DK=DV=256, H=128
#define B_   4
#define LQ_  256
#define LK_  512
#define DQK_ 256
#define DV_  256
#define H_   128

// ---------------------------------------------------------------------------
// proj_kernel: out[r, h] = sum_d in[r, d] * W[d, h]
// one block per row, 128 threads (h index). W reads coalesced across threads.
// ---------------------------------------------------------------------------
__global__ __launch_bounds__(H_) void proj_kernel(const float* __restrict__ in,
                                                  const float* __restrict__ W,
                                                  float* __restrict__ out) {
    __shared__ float row[DQK_];
    const int r = blockIdx.x;
    const int t = threadIdx.x;
    row[t]        = in[r * DQK_ + t];
    row[t + H_]   = in[r * DQK_ + t + H_];
    __syncthreads();
    float acc = 0.f;
#pragma unroll 8
    for (int d = 0; d < DQK_; ++d) {
        acc += row[d] * W[d * H_ + t];
    }
    out[r * H_ + t] = acc;
}

// ---------------------------------------------------------------------------
// attn_kernel: one block per (b, q) pair. 256 threads.
//   Phase A: stage q-row (H=128) in LDS
//   Phase B: each thread computes 2 scores (k = t, t+256): sum_h wv[h]*tanh(q+k)
//   Phase C: masked softmax over LK=512 in LDS
//   Phase D: out[b,q,v] = sum_k attn[k]*values[b,k,v], v = threadIdx (coalesced)
// ---------------------------------------------------------------------------
__global__ __launch_bounds__(256) void attn_kernel(
    const float* __restrict__ qp,          // [B*LQ, H]
    const float* __restrict__ kp,          // [B*LK, H]
    const float* __restrict__ wv,          // [H]
    const float* __restrict__ values,      // [B, LK, DV]
    const int*   __restrict__ valid_lens,  // [B]
    float* __restrict__ out) {             // [B*LQ, DV]
    __shared__ float qrow[H_];
    __shared__ float sc[LK_];
    __shared__ float red[8];

    const int bq = blockIdx.x;       // 0..B*LQ-1
    const int b  = bq >> 8;          // LQ = 256
    const int t  = threadIdx.x;

    if (t < H_) qrow[t] = qp[bq * H_ + t];
    __syncthreads();

    const int valid = valid_lens[b];

    // ---- Phase B: scores ----
    const float4* q4 = reinterpret_cast<const float4*>(qrow);
    const float4* w4 = reinterpret_cast<const float4*>(wv);
    for (int kk = t; kk < LK_; kk += 256) {
        const float4* krow = reinterpret_cast<const float4*>(kp + (size_t)(b * LK_ + kk) * H_);
        float s = 0.f;
#pragma unroll 8
        for (int h4 = 0; h4 < H_ / 4; ++h4) {
            float4 kv = krow[h4];
            float4 qv = q4[h4];
            float4 wvv = w4[h4];
            s += wvv.x * tanhf(qv.x + kv.x);
            s += wvv.y * tanhf(qv.y + kv.y);
            s += wvv.z * tanhf(qv.z + kv.z);
            s += wvv.w * tanhf(qv.w + kv.w);
        }
        sc[kk] = (kk < valid) ? s : -1e6f;
    }
    __syncthreads();

    // ---- Phase C: masked softmax over sc[0..511] ----
    // max reduction (valid >= 1 guarantees at least one real score)
    float m = fmaxf(sc[t], sc[t + 256]);
#pragma unroll
    for (int off = 32; off; off >>= 1) m = fmaxf(m, __shfl_down(m, off, 64));
    if ((t & 63) == 0) red[t >> 6] = m;
    __syncthreads();
    if (t == 0) red[4] = fmaxf(fmaxf(red[0], red[1]), fmaxf(red[2], red[3]));
    __syncthreads();
    m = red[4];

    // exp + sum
    float e0 = expf(sc[t] - m);
    float e1 = expf(sc[t + 256] - m);
    sc[t]       = e0;
    sc[t + 256] = e1;
    float s = e0 + e1;
#pragma unroll
    for (int off = 32; off; off >>= 1) s += __shfl_down(s, off, 64);
    if ((t & 63) == 0) red[t >> 6] = s;
    __syncthreads();
    if (t == 0) red[5] = red[0] + red[1] + red[2] + red[3];
    __syncthreads();
    const float inv = 1.f / red[5];

    // ---- Phase D: out = attn @ values ----
    float acc = 0.f;
    const float* vb = values + (size_t)b * LK_ * DV_ + t;  // coalesced over t
#pragma unroll 8
    for (int k = 0; k < LK_; ++k) {
        acc += sc[k] * vb[(size_t)k * DV_];
    }
    out[(size_t)bq * DV_ + t] = acc * inv;
}

extern "C" void kernel_launch(void* const* d_in, const int* in_sizes, int n_in,
                              void* d_out, int out_size, void* d_ws, size_t ws_size,
                              hipStream_t stream) {
    const float* queries    = (const float*)d_in[0];  // [B, LQ, DQ]
    const float* keys       = (const float*)d_in[1];  // [B, LK, DK]
    const float* values     = (const float*)d_in[2];  // [B, LK, DV]
    const float* Wq         = (const float*)d_in[3];  // [DQ, H]
    const float* Wk         = (const float*)d_in[4];  // [DK, H]
    const float* wv         = (const float*)d_in[5];  // [H]
    const int*   valid_lens = (const int*)d_in[6];    // [B]
    float* out = (float*)d_out;

    float* qp = (float*)d_ws;                  // [B*LQ, H]  = 512 KB
    float* kp = qp + (size_t)B_ * LQ_ * H_;    // [B*LK, H]  = 1 MB

    proj_kernel<<<B_ * LQ_, H_, 0, stream>>>(queries, Wq, qp);
    proj_kernel<<<B_ * LK_, H_, 0, stream>>>(keys, Wk, kp);
    attn_kernel<<<B_ * LQ_, 256, 0, stream>>>(qp, kp, wv, values, valid_lens, out);
}

// Round 2
// 68.347 us; speedup vs baseline: 1.5137x; 1.5137x over previous
//
#include <hip/hip_runtime.h>

// Problem constants: B=4, LQ=256, LK=512, DQ=DK=DV=256, H=128
#define B_   4
#define LQ_  256
#define LK_  512
#define DQK_ 256
#define DV_  256
#define H_   128

#define TANH_C 2.8853900817779268f   // 2*log2(e): tanh(x) = 1 - 2/(exp2(TANH_C*x)+1)
#define L2E    1.4426950408889634f

// ---------------------------------------------------------------------------
// proj_kernel: out[r, h] = TANH_C * sum_d in[r, d] * W[d, h]
// (pre-scaled so the attn kernel's exp2 argument is just qs+ks)
// ---------------------------------------------------------------------------
__global__ __launch_bounds__(H_) void proj_kernel(const float* __restrict__ in,
                                                  const float* __restrict__ W,
                                                  float* __restrict__ out) {
    __shared__ float row[DQK_];
    const int r = blockIdx.x;
    const int t = threadIdx.x;
    row[t]      = in[r * DQK_ + t];
    row[t + H_] = in[r * DQK_ + t + H_];
    __syncthreads();
    float acc = 0.f;
#pragma unroll 8
    for (int d = 0; d < DQK_; ++d) {
        acc += row[d] * W[d * H_ + t];
    }
    out[r * H_ + t] = acc * TANH_C;
}

// ---------------------------------------------------------------------------
// attn_kernel: one block per (b, q). 512 threads (8 waves -> 100% occupancy cap).
//   score[k] (thread k): sum_h wm2[h] * rcp(1 + exp2(qs[h] + ks[h]))
//     == sum_h wv[h]*tanh(q+k) minus the constant sum(wv) (cancels in softmax)
//   masked softmax over LK=512, then out[v] = sum_k attn[k]*values[b,k,v]
// ---------------------------------------------------------------------------
__global__ __launch_bounds__(512) void attn_kernel(
    const float* __restrict__ qp,          // [B*LQ, H]   (scaled by TANH_C)
    const float* __restrict__ kp,          // [B*LK, H]   (scaled by TANH_C)
    const float* __restrict__ wv,          // [H]
    const float* __restrict__ values,      // [B, LK, DV]
    const int*   __restrict__ valid_lens,  // [B]
    float* __restrict__ out) {             // [B*LQ, DV]
    __shared__ float qs[H_];
    __shared__ float wm2[H_];
    __shared__ float sc[LK_];
    __shared__ float part[512];
    __shared__ float red[16];

    const int bq = blockIdx.x;       // 0..B*LQ-1
    const int b  = bq >> 8;          // LQ = 256
    const int t  = threadIdx.x;      // 0..511

    if (t < H_) {
        qs[t]  = qp[bq * H_ + t];
        wm2[t] = -2.f * wv[t];
    }
    __syncthreads();

    const int valid = valid_lens[b];

    // ---- scores: thread t handles k = t ----
    const float4* q4 = reinterpret_cast<const float4*>(qs);
    const float4* w4 = reinterpret_cast<const float4*>(wm2);
    const float4* k4 = reinterpret_cast<const float4*>(kp + (size_t)(b * LK_ + t) * H_);
    float s = 0.f;
#pragma unroll 8
    for (int h4 = 0; h4 < H_ / 4; ++h4) {
        float4 kv = k4[h4];
        float4 qv = q4[h4];
        float4 wm = w4[h4];
        s += wm.x * __builtin_amdgcn_rcpf(1.f + __builtin_amdgcn_exp2f(qv.x + kv.x));
        s += wm.y * __builtin_amdgcn_rcpf(1.f + __builtin_amdgcn_exp2f(qv.y + kv.y));
        s += wm.z * __builtin_amdgcn_rcpf(1.f + __builtin_amdgcn_exp2f(qv.z + kv.z));
        s += wm.w * __builtin_amdgcn_rcpf(1.f + __builtin_amdgcn_exp2f(qv.w + kv.w));
    }
    s = (t < valid) ? s : -1e6f;

    // ---- masked softmax over 512 scores (8 waves) ----
    float m = s;
#pragma unroll
    for (int off = 32; off; off >>= 1) m = fmaxf(m, __shfl_down(m, off, 64));
    if ((t & 63) == 0) red[t >> 6] = m;
    __syncthreads();
    if (t == 0) {
        float mm = red[0];
#pragma unroll
        for (int i = 1; i < 8; ++i) mm = fmaxf(mm, red[i]);
        red[8] = mm;
    }
    __syncthreads();
    m = red[8];

    float e = __builtin_amdgcn_exp2f((s - m) * L2E);
    sc[t] = e;
    float ss = e;
#pragma unroll
    for (int off = 32; off; off >>= 1) ss += __shfl_down(ss, off, 64);
    if ((t & 63) == 0) red[t >> 6] = ss;
    __syncthreads();
    if (t == 0) {
        float tt = red[0];
#pragma unroll
        for (int i = 1; i < 8; ++i) tt += red[i];
        red[9] = tt;
    }
    __syncthreads();
    const float inv = 1.f / red[9];

    // ---- out = attn @ values: thread (half, v) does half the k range ----
    const int v    = t & 255;
    const int half = t >> 8;
    const float* vb = values + (size_t)b * LK_ * DV_ + (size_t)half * 256 * DV_ + v;
    const float* sh = sc + half * 256;
    float acc = 0.f;
#pragma unroll 8
    for (int k = 0; k < 256; ++k) {
        acc += sh[k] * vb[(size_t)k * DV_];
    }
    part[t] = acc;
    __syncthreads();
    if (t < 256) {
        out[(size_t)bq * DV_ + t] = (part[t] + part[t + 256]) * inv;
    }
}

extern "C" void kernel_launch(void* const* d_in, const int* in_sizes, int n_in,
                              void* d_out, int out_size, void* d_ws, size_t ws_size,
                              hipStream_t stream) {
    const float* queries    = (const float*)d_in[0];  // [B, LQ, DQ]
    const float* keys       = (const float*)d_in[1];  // [B, LK, DK]
    const float* values     = (const float*)d_in[2];  // [B, LK, DV]
    const float* Wq         = (const float*)d_in[3];  // [DQ, H]
    const float* Wk         = (const float*)d_in[4];  // [DK, H]
    const float* wv         = (const float*)d_in[5];  // [H]
    const int*   valid_lens = (const int*)d_in[6];    // [B]
    float* out = (float*)d_out;

    float* qp = (float*)d_ws;                  // [B*LQ, H]  = 512 KB
    float* kp = qp + (size_t)B_ * LQ_ * H_;    // [B*LK, H]  = 1 MB

    proj_kernel<<<B_ * LQ_, H_, 0, stream>>>(queries, Wq, qp);
    proj_kernel<<<B_ * LK_, H_, 0, stream>>>(keys, Wk, kp);
    attn_kernel<<<B_ * LQ_, 512, 0, stream>>>(qp, kp, wv, values, valid_lens, out);
}

// Round 3
// 49.187 us; speedup vs baseline: 2.1034x; 1.3895x over previous
//
#include <hip/hip_runtime.h>

// B=4, LQ=256, LK=512, DQ=DK=DV=256, H=128
#define B_   4
#define LQ_  256
#define LK_  512
#define DQK_ 256
#define DV_  256
#define H_   128

#define TANH_C 2.8853900817779268f   // 2*log2(e): tanh(x) = 1 - 2/(exp2(TANH_C*x)+1)
#define L2E    1.4426950408889634f

// ---------------------------------------------------------------------------
// proj_kernel<TILE,TR>: 8 rows per block, 128 threads (t = h).
//   acc[j] = sum_d in[r0+j, d] * W[d, t]   (rows read via scalar/K$ loads)
//   TR=false: out[r, h]        (for q: [B*LQ, H])
//   TR=true : out[b, h, k]     (for k: [B, H, LK]  -> coalesced attn reads)
// Both outputs pre-scaled by TANH_C.
// ---------------------------------------------------------------------------
template<int TILE, bool TR>
__global__ __launch_bounds__(128) void proj_kernel(const float* __restrict__ in,
                                                   const float* __restrict__ W,
                                                   float* __restrict__ out) {
    const int r0 = blockIdx.x * TILE;
    const int t  = threadIdx.x;
    float acc[TILE];
#pragma unroll
    for (int j = 0; j < TILE; ++j) acc[j] = 0.f;

    const float4* in4 = reinterpret_cast<const float4*>(in + (size_t)r0 * DQK_);
    for (int d4 = 0; d4 < DQK_ / 4; ++d4) {
        float4 rv[TILE];
#pragma unroll
        for (int j = 0; j < TILE; ++j) rv[j] = in4[j * (DQK_ / 4) + d4];  // uniform -> s_load
#pragma unroll
        for (int e = 0; e < 4; ++e) {
            float w = W[(size_t)(4 * d4 + e) * H_ + t];                   // coalesced
#pragma unroll
            for (int j = 0; j < TILE; ++j)
                acc[j] = fmaf(reinterpret_cast<const float*>(&rv[j])[e], w, acc[j]);
        }
    }
    if (TR) {
        const int b  = r0 >> 9;          // r0 / LK_
        const int k0 = r0 & (LK_ - 1);
        float* o = out + ((size_t)(b * H_ + t)) * LK_ + k0;
        float4 lo = make_float4(acc[0] * TANH_C, acc[1] * TANH_C, acc[2] * TANH_C, acc[3] * TANH_C);
        float4 hi = make_float4(acc[4] * TANH_C, acc[5] * TANH_C, acc[6] * TANH_C, acc[7] * TANH_C);
        *reinterpret_cast<float4*>(o)     = lo;
        *reinterpret_cast<float4*>(o + 4) = hi;
    } else {
#pragma unroll
        for (int j = 0; j < TILE; ++j)
            out[(size_t)(r0 + j) * H_ + t] = acc[j] * TANH_C;
    }
}

// ---------------------------------------------------------------------------
// attn_kernel: one block per (b, q-tile of 4). 1024 threads (16 waves).
//  Phase B: thread (qh=t>>9, k=t&511) computes scores for 2 q-rows at its k:
//           s = -2 * sum_h wv[h] * rcp(1 + exp2(qs[h] + ks[h]))   (+const, cancels)
//           k >= valid -> -1e6.  k-loads coalesced via kpT[b][h][k]; q,wv scalar.
//  Softmax: per-row (4 rows) masked softmax over 512 scores, all 16 waves.
//  Phase D: thread (kh=t>>8, v=t&255) accumulates 4 qi-partials over its
//           k-range (clamped to valid), LDS cross-reduce, scale by 1/sum.
// ---------------------------------------------------------------------------
__global__ __launch_bounds__(1024) void attn_kernel(
    const float* __restrict__ qp,          // [B*LQ, H]   (TANH_C-scaled)
    const float* __restrict__ kpT,         // [B, H, LK]  (TANH_C-scaled)
    const float* __restrict__ wv,          // [H]
    const float* __restrict__ values,      // [B, LK, DV]
    const int*   __restrict__ valid_lens,  // [B]
    float* __restrict__ out) {             // [B*LQ, DV]
    __shared__ float sc[LK_][4];           // [k][qi]  8 KB
    __shared__ float part[4][4][DV_];      // [kh][qi][v] 16 KB
    __shared__ float red[20];
    __shared__ float inv_s[4];

    const int blk = blockIdx.x;            // b*64 + qt
    const int b   = blk >> 6;
    const int qt  = blk & 63;
    const int t   = threadIdx.x;
    const int valid = valid_lens[b];

    // ---- Phase B: scores ----
    {
        const int k  = t & 511;
        const int qh = __builtin_amdgcn_readfirstlane(t >> 9);   // 0/1, wave-uniform
        float2 s2;
        if (k < valid) {
            const float* q0   = qp + (size_t)(b * LQ_ + qt * 4 + 2 * qh) * H_;
            const float* q1   = q0 + H_;
            const float* kcol = kpT + (size_t)b * H_ * LK_ + k;
            float p0 = 0.f, p1 = 0.f;
#pragma unroll 4
            for (int h = 0; h < H_; ++h) {
                float kv = kcol[(size_t)h * LK_];                 // coalesced over k
                float w  = wv[h];                                 // scalar
                float r0 = __builtin_amdgcn_rcpf(1.f + __builtin_amdgcn_exp2f(q0[h] + kv));
                float r1 = __builtin_amdgcn_rcpf(1.f + __builtin_amdgcn_exp2f(q1[h] + kv));
                p0 = fmaf(w, r0, p0);
                p1 = fmaf(w, r1, p1);
            }
            s2 = make_float2(-2.f * p0, -2.f * p1);
        } else {
            s2 = make_float2(-1e6f, -1e6f);
        }
        *reinterpret_cast<float2*>(&sc[k][2 * qh]) = s2;
    }
    __syncthreads();

    // ---- masked softmax: 16 waves, wave w -> row qi = w>>2 ----
    const int qi = t >> 8;                 // 0..3, wave-uniform
    const int kl = t & 255;
    float s0 = sc[kl][qi], s1 = sc[kl + 256][qi];
    {
        float m = fmaxf(s0, s1);
#pragma unroll
        for (int off = 32; off; off >>= 1) m = fmaxf(m, __shfl_down(m, off, 64));
        if ((t & 63) == 0) red[t >> 6] = m;
    }
    __syncthreads();
    if (t < 4) {
        float m = fmaxf(fmaxf(red[4 * t], red[4 * t + 1]), fmaxf(red[4 * t + 2], red[4 * t + 3]));
        red[16 + t] = m;
    }
    __syncthreads();
    {
        const float m = red[16 + qi];
        float e0 = __builtin_amdgcn_exp2f((s0 - m) * L2E);
        float e1 = __builtin_amdgcn_exp2f((s1 - m) * L2E);
        sc[kl][qi]       = e0;
        sc[kl + 256][qi] = e1;
        float ss = e0 + e1;
#pragma unroll
        for (int off = 32; off; off >>= 1) ss += __shfl_down(ss, off, 64);
        if ((t & 63) == 0) red[t >> 6] = ss;
    }
    __syncthreads();
    if (t < 4) {
        inv_s[t] = 1.f / (red[4 * t] + red[4 * t + 1] + red[4 * t + 2] + red[4 * t + 3]);
    }
    __syncthreads();

    // ---- Phase D: out = attn @ values ----
    {
        const int kh = __builtin_amdgcn_readfirstlane(t >> 8);   // 0..3
        const int v  = t & 255;
        const int kstart = kh * 128;
        const int kend   = min(kstart + 128, valid);             // sc==0 beyond valid
        const float* vb = values + (size_t)b * LK_ * DV_ + v;
        float a0 = 0.f, a1 = 0.f, a2 = 0.f, a3 = 0.f;
#pragma unroll 4
        for (int k = kstart; k < kend; ++k) {
            float4 f  = *reinterpret_cast<const float4*>(&sc[k][0]);  // LDS broadcast
            float val = vb[(size_t)k * DV_];                          // coalesced over v
            a0 = fmaf(f.x, val, a0);
            a1 = fmaf(f.y, val, a1);
            a2 = fmaf(f.z, val, a2);
            a3 = fmaf(f.w, val, a3);
        }
        part[kh][0][v] = a0;
        part[kh][1][v] = a1;
        part[kh][2][v] = a2;
        part[kh][3][v] = a3;
    }
    __syncthreads();
    {
        const int v = t & 255;
        float r = (part[0][qi][v] + part[1][qi][v]) + (part[2][qi][v] + part[3][qi][v]);
        out[(size_t)(b * LQ_ + qt * 4 + qi) * DV_ + v] = r * inv_s[qi];
    }
}

extern "C" void kernel_launch(void* const* d_in, const int* in_sizes, int n_in,
                              void* d_out, int out_size, void* d_ws, size_t ws_size,
                              hipStream_t stream) {
    const float* queries    = (const float*)d_in[0];  // [B, LQ, DQ]
    const float* keys       = (const float*)d_in[1];  // [B, LK, DK]
    const float* values     = (const float*)d_in[2];  // [B, LK, DV]
    const float* Wq         = (const float*)d_in[3];  // [DQ, H]
    const float* Wk         = (const float*)d_in[4];  // [DK, H]
    const float* wv         = (const float*)d_in[5];  // [H]
    const int*   valid_lens = (const int*)d_in[6];    // [B]
    float* out = (float*)d_out;

    float* qp  = (float*)d_ws;                   // [B*LQ, H]   512 KB
    float* kpT = qp + (size_t)B_ * LQ_ * H_;     // [B, H, LK]  1 MB

    proj_kernel<8, false><<<B_ * LQ_ / 8, 128, 0, stream>>>(queries, Wq, qp);
    proj_kernel<8, true ><<<B_ * LK_ / 8, 128, 0, stream>>>(keys, Wk, kpT);
    attn_kernel<<<B_ * LQ_ / 4, 1024, 0, stream>>>(qp, kpT, wv, values, valid_lens, out);
}

// Round 4
// 30.444 us; speedup vs baseline: 3.3983x; 1.6157x over previous
//
#include <hip/hip_runtime.h>

// B=4, LQ=256, LK=512, DQ=DK=DV=256, H=128
#define B_   4
#define LQ_  256
#define LK_  512
#define DQK_ 256
#define DV_  256
#define H_   128

#define TANH_C 2.8853900817779268f   // 2*log2(e): tanh(x) = 1 - 2/(exp2(TANH_C*x)+1)
#define L2E    1.4426950408889634f
#define NQBLK (B_ * LQ_ / 4)         // 256 q-proj blocks (TILE=4)
#define NKBLK (B_ * LK_ / 4)         // 512 k-proj blocks

// ---------------------------------------------------------------------------
// proj_kernel: fused q+k projection. TILE=4 rows/block, 128 threads (t=h).
//   blocks [0, NQBLK)          -> eq [B*LQ, H]  = exp2(TANH_C * q@Wq)
//   blocks [NQBLK, NQBLK+NKBLK)-> ekT [B, H, LK] = exp2(TANH_C * k@Wk), transposed
// ---------------------------------------------------------------------------
__global__ __launch_bounds__(128) void proj_kernel(const float* __restrict__ Q,
                                                   const float* __restrict__ K,
                                                   const float* __restrict__ Wq,
                                                   const float* __restrict__ Wk,
                                                   float* __restrict__ eq,
                                                   float* __restrict__ ekT) {
    const int blk = blockIdx.x;
    const bool isq = blk < NQBLK;
    const float* in = isq ? Q  : K;
    const float* W  = isq ? Wq : Wk;
    const int r0 = (isq ? blk : blk - NQBLK) * 4;
    const int t  = threadIdx.x;

    float acc0 = 0.f, acc1 = 0.f, acc2 = 0.f, acc3 = 0.f;
    const float4* in4 = reinterpret_cast<const float4*>(in + (size_t)r0 * DQK_);
    for (int d4 = 0; d4 < DQK_ / 4; ++d4) {
        float4 r0v = in4[0 * (DQK_ / 4) + d4];   // uniform -> s_load
        float4 r1v = in4[1 * (DQK_ / 4) + d4];
        float4 r2v = in4[2 * (DQK_ / 4) + d4];
        float4 r3v = in4[3 * (DQK_ / 4) + d4];
#pragma unroll
        for (int e = 0; e < 4; ++e) {
            float w = W[(size_t)(4 * d4 + e) * H_ + t];   // coalesced
            acc0 = fmaf(reinterpret_cast<const float*>(&r0v)[e], w, acc0);
            acc1 = fmaf(reinterpret_cast<const float*>(&r1v)[e], w, acc1);
            acc2 = fmaf(reinterpret_cast<const float*>(&r2v)[e], w, acc2);
            acc3 = fmaf(reinterpret_cast<const float*>(&r3v)[e], w, acc3);
        }
    }
    float e0 = __builtin_amdgcn_exp2f(acc0 * TANH_C);
    float e1 = __builtin_amdgcn_exp2f(acc1 * TANH_C);
    float e2 = __builtin_amdgcn_exp2f(acc2 * TANH_C);
    float e3 = __builtin_amdgcn_exp2f(acc3 * TANH_C);
    if (isq) {
        eq[(size_t)(r0 + 0) * H_ + t] = e0;
        eq[(size_t)(r0 + 1) * H_ + t] = e1;
        eq[(size_t)(r0 + 2) * H_ + t] = e2;
        eq[(size_t)(r0 + 3) * H_ + t] = e3;
    } else {
        const int b  = r0 >> 9;
        const int k0 = r0 & (LK_ - 1);
        float* o = ekT + ((size_t)(b * H_ + t)) * LK_ + k0;
        *reinterpret_cast<float4*>(o) = make_float4(e0, e1, e2, e3);
    }
}

// ---------------------------------------------------------------------------
// attn_kernel: one block per (b, q-tile of 4). 1024 threads (16 waves).
//  Stage: Eq rows (4x128) + wm2 = -2*wv in LDS (broadcast-read later).
//  Phase B: thread (pair=t>>9, k=t&511): 2 qi chains;
//           p += wm2[h] * rcp(fma(Eq[qi][h], Ek[h][k], 1.0))  -- 1 trans/elem
//  Phase C: per-row masked softmax over 512 (16 waves, 4 rows).
//  Phase D: thread (kh=t>>8, v=t&255): 4 qi partials over k-range, LDS reduce.
// ---------------------------------------------------------------------------
__global__ __launch_bounds__(1024) void attn_kernel(
    const float* __restrict__ eq,          // [B*LQ, H]
    const float* __restrict__ ekT,         // [B, H, LK]
    const float* __restrict__ wv,          // [H]
    const float* __restrict__ values,      // [B, LK, DV]
    const int*   __restrict__ valid_lens,  // [B]
    float* __restrict__ out) {             // [B*LQ, DV]
    __shared__ float eq_l[4][H_];          // 2 KB
    __shared__ float wm2[H_];              // 512 B
    __shared__ float sc[LK_][4];           // 8 KB
    __shared__ float part[4][4][DV_];      // 16 KB
    __shared__ float red[20];
    __shared__ float inv_s[4];

    const int blk = blockIdx.x;            // b*64 + qt
    const int b   = blk >> 6;
    const int qt  = blk & 63;
    const int t   = threadIdx.x;

    if (t < 512) {
        eq_l[t >> 7][t & 127] = eq[(size_t)(b * LQ_ + qt * 4 + (t >> 7)) * H_ + (t & 127)];
    } else if (t < 640) {
        wm2[t - 512] = -2.f * wv[t - 512];
    }
    __syncthreads();

    const int valid = valid_lens[b];

    // ---- Phase B: scores ----
    {
        const int k    = t & 511;
        const int pair = __builtin_amdgcn_readfirstlane(t >> 9);  // 0/1 wave-uniform
        float2 s2 = make_float2(-1e6f, -1e6f);
        if (k < valid) {
            const float* ekp = ekT + (size_t)b * H_ * LK_ + k;
            const float4* w4  = reinterpret_cast<const float4*>(wm2);
            const float4* qa4 = reinterpret_cast<const float4*>(eq_l[2 * pair]);
            const float4* qb4 = reinterpret_cast<const float4*>(eq_l[2 * pair + 1]);
            float p0 = 0.f, p1 = 0.f;
#pragma unroll 4
            for (int h4 = 0; h4 < H_ / 4; ++h4) {
                float4 w  = w4[h4];
                float4 qa = qa4[h4];
                float4 qb = qb4[h4];
#pragma unroll
                for (int e = 0; e < 4; ++e) {
                    float ek = ekp[(size_t)(4 * h4 + e) * LK_];   // coalesced over k
                    float fa = fmaf(reinterpret_cast<const float*>(&qa)[e], ek, 1.f);
                    float fb = fmaf(reinterpret_cast<const float*>(&qb)[e], ek, 1.f);
                    float ww = reinterpret_cast<const float*>(&w)[e];
                    p0 = fmaf(ww, __builtin_amdgcn_rcpf(fa), p0);
                    p1 = fmaf(ww, __builtin_amdgcn_rcpf(fb), p1);
                }
            }
            s2 = make_float2(p0, p1);      // -2 folded into wm2; +sum(wv) cancels
        }
        *reinterpret_cast<float2*>(&sc[k][2 * pair]) = s2;
    }
    __syncthreads();

    // ---- Phase C: masked softmax (wave w -> row qi = w>>2) ----
    const int qi = t >> 8;                 // 0..3 wave-uniform
    const int kl = t & 255;
    float s0 = sc[kl][qi], s1 = sc[kl + 256][qi];
    {
        float m = fmaxf(s0, s1);
#pragma unroll
        for (int off = 32; off; off >>= 1) m = fmaxf(m, __shfl_down(m, off, 64));
        if ((t & 63) == 0) red[t >> 6] = m;
    }
    __syncthreads();
    if (t < 4) {
        red[16 + t] = fmaxf(fmaxf(red[4 * t], red[4 * t + 1]),
                            fmaxf(red[4 * t + 2], red[4 * t + 3]));
    }
    __syncthreads();
    {
        const float m = red[16 + qi];
        float e0 = __builtin_amdgcn_exp2f((s0 - m) * L2E);
        float e1 = __builtin_amdgcn_exp2f((s1 - m) * L2E);
        sc[kl][qi]       = e0;
        sc[kl + 256][qi] = e1;
        float ss = e0 + e1;
#pragma unroll
        for (int off = 32; off; off >>= 1) ss += __shfl_down(ss, off, 64);
        if ((t & 63) == 0) red[t >> 6] = ss;
    }
    __syncthreads();
    if (t < 4) {
        inv_s[t] = 1.f / (red[4 * t] + red[4 * t + 1] + red[4 * t + 2] + red[4 * t + 3]);
    }
    __syncthreads();

    // ---- Phase D: out = attn @ values ----
    {
        const int kh = __builtin_amdgcn_readfirstlane(t >> 8);   // 0..3
        const int v  = t & 255;
        const int kstart = kh * 128;
        const int kend   = min(kstart + 128, valid);             // sc==0 beyond valid
        const float* vb = values + (size_t)b * LK_ * DV_ + v;
        float a0 = 0.f, a1 = 0.f, a2 = 0.f, a3 = 0.f;
#pragma unroll 4
        for (int k = kstart; k < kend; ++k) {
            float4 f  = *reinterpret_cast<const float4*>(&sc[k][0]);  // LDS broadcast
            float val = vb[(size_t)k * DV_];                          // coalesced over v
            a0 = fmaf(f.x, val, a0);
            a1 = fmaf(f.y, val, a1);
            a2 = fmaf(f.z, val, a2);
            a3 = fmaf(f.w, val, a3);
        }
        part[kh][0][v] = a0;
        part[kh][1][v] = a1;
        part[kh][2][v] = a2;
        part[kh][3][v] = a3;
    }
    __syncthreads();
    {
        const int v = t & 255;
        float r = (part[0][qi][v] + part[1][qi][v]) + (part[2][qi][v] + part[3][qi][v]);
        out[(size_t)(b * LQ_ + qt * 4 + qi) * DV_ + v] = r * inv_s[qi];
    }
}

extern "C" void kernel_launch(void* const* d_in, const int* in_sizes, int n_in,
                              void* d_out, int out_size, void* d_ws, size_t ws_size,
                              hipStream_t stream) {
    const float* queries    = (const float*)d_in[0];  // [B, LQ, DQ]
    const float* keys       = (const float*)d_in[1];  // [B, LK, DK]
    const float* values     = (const float*)d_in[2];  // [B, LK, DV]
    const float* Wq         = (const float*)d_in[3];  // [DQ, H]
    const float* Wk         = (const float*)d_in[4];  // [DK, H]
    const float* wv         = (const float*)d_in[5];  // [H]
    const int*   valid_lens = (const int*)d_in[6];    // [B]
    float* out = (float*)d_out;

    float* eq  = (float*)d_ws;                   // [B*LQ, H]   512 KB
    float* ekT = eq + (size_t)B_ * LQ_ * H_;     // [B, H, LK]  1 MB

    proj_kernel<<<NQBLK + NKBLK, 128, 0, stream>>>(queries, keys, Wq, Wk, eq, ekT);
    attn_kernel<<<B_ * LQ_ / 4, 1024, 0, stream>>>(eq, ekT, wv, values, valid_lens, out);
}